// Round 1
// baseline (763.543 us; speedup 1.0000x reference)
//
#include <hip/hip_runtime.h>
#include <hip/hip_bf16.h>
#include <stdint.h>

// SparseMoE: top-2 of 8 experts, N=8192 tokens, D=1024, H=2048, fp32 in/out.
// Strategy: fp32 router (exact top-k selection) + bf16 MFMA grouped GEMMs over
// gathered per-expert token lists (4x less work than dense). m97-style 128x128
// tiles with global_load_lds staging. Deterministic: combine pass, no atomics
// on the output.

#define N_TOK 8192
#define D_DIM 1024
#define H_DIM 2048
#define N_EXP 8
#define N_ASSIGN (N_TOK * 2)

typedef __attribute__((ext_vector_type(8))) short short8;   // bf16x8 MFMA frag
typedef __attribute__((ext_vector_type(4))) float f32x4;    // MFMA acc frag

__device__ __forceinline__ unsigned short f2bf(float f) {
  union { float f; unsigned int u; } v; v.f = f;
  unsigned int r = v.u + 0x7fffu + ((v.u >> 16) & 1u);  // RTNE
  return (unsigned short)(r >> 16);
}
__device__ __forceinline__ float bf2f(unsigned short u) {
  union { float f; unsigned int u; } v; v.u = ((unsigned int)u) << 16; return v.f;
}
__device__ __forceinline__ void gload_lds16(const void* g, void* l) {
  __builtin_amdgcn_global_load_lds((const __attribute__((address_space(1))) void*)g,
                                   (__attribute__((address_space(3))) void*)l, 16, 0, 0);
}

// ---------------- tiny setup kernels ----------------
__global__ void zero_cnt_kernel(int* cnt) {
  if (threadIdx.x < N_EXP) cnt[threadIdx.x] = 0;
}

__global__ void cvt_bf16_kernel(const float* __restrict__ src,
                                unsigned short* __restrict__ dst, int n) {
  int i = (blockIdx.x * 256 + threadIdx.x) * 4;
  if (i >= n) return;
  float4 v = *(const float4*)(src + i);
  ushort4 o;
  o.x = f2bf(v.x); o.y = f2bf(v.y); o.z = f2bf(v.z); o.w = f2bf(v.w);
  *(ushort4*)(dst + i) = o;
}

// ---------------- router: fp32 logits, softmax, top-2, slot assignment ------
__global__ __launch_bounds__(256) void router_kernel(
    const float* __restrict__ x, const float* __restrict__ rw,
    const float* __restrict__ rb,
    unsigned short* __restrict__ xb,          // bf16 copy of x
    int4* __restrict__ tiidx,                 // (e1,e2,slot1,slot2)
    float2* __restrict__ tiw,                 // (w1,w2) normalized
    int* __restrict__ cnt) {
  __shared__ float sw[N_EXP][D_DIM];          // 32 KB router weights
  int tid = threadIdx.x;
  for (int i = tid * 4; i < N_EXP * D_DIM; i += 256 * 4)
    *(float4*)&sw[0][i] = *(const float4*)(rw + i);
  __syncthreads();

  int wave = tid >> 6, lane = tid & 63;
  int t = blockIdx.x * 4 + wave;
  const float* xr = x + (size_t)t * D_DIM;
  float xs[16];
#pragma unroll
  for (int j = 0; j < 16; j++) xs[j] = xr[lane + 64 * j];
  // emit bf16 x (coalesced enough; saves a separate pass over x)
#pragma unroll
  for (int j = 0; j < 16; j++) xb[(size_t)t * D_DIM + lane + 64 * j] = f2bf(xs[j]);

  float logit[N_EXP];
#pragma unroll
  for (int e = 0; e < N_EXP; e++) {
    float acc = 0.f;
#pragma unroll
    for (int j = 0; j < 16; j++) acc += xs[j] * sw[e][lane + 64 * j];
#pragma unroll
    for (int off = 32; off; off >>= 1) acc += __shfl_xor(acc, off);
    logit[e] = acc + rb[e];
  }
  if (lane == 0) {
    float m = logit[0];
#pragma unroll
    for (int e = 1; e < N_EXP; e++) m = fmaxf(m, logit[e]);
    float p[N_EXP], S = 0.f;
#pragma unroll
    for (int e = 0; e < N_EXP; e++) { p[e] = expf(logit[e] - m); S += p[e]; }
#pragma unroll
    for (int e = 0; e < N_EXP; e++) p[e] /= S;   // select on probs like the ref
    int i1 = 0; float v1 = p[0];
#pragma unroll
    for (int e = 1; e < N_EXP; e++) if (p[e] > v1) { v1 = p[e]; i1 = e; }
    int i2 = -1; float v2 = -1.f;
#pragma unroll
    for (int e = 0; e < N_EXP; e++) if (e != i1 && p[e] > v2) { v2 = p[e]; i2 = e; }
    float inv = 1.f / (v1 + v2 + 1e-9f);
    int s1 = atomicAdd(&cnt[i1], 1);
    int s2 = atomicAdd(&cnt[i2], 1);
    tiidx[t] = make_int4(i1, i2, s1, s2);
    tiw[t] = make_float2(v1 * inv, v2 * inv);
  }
}

__global__ void offsets_kernel(const int* __restrict__ cnt, int* __restrict__ off) {
  if (threadIdx.x == 0) {
    int a = 0;
    for (int e = 0; e < N_EXP; e++) { off[e] = a; a += cnt[e]; }
    off[N_EXP] = a;
  }
}

__global__ void scatter_kernel(const int4* __restrict__ tiidx,
                               const int* __restrict__ off,
                               int* __restrict__ assign, int2* __restrict__ trows) {
  int t = blockIdx.x * 256 + threadIdx.x;
  if (t >= N_TOK) return;
  int4 ti = tiidx[t];
  int r1 = off[ti.x] + ti.z;
  int r2 = off[ti.y] + ti.w;
  assign[r1] = t;
  assign[r2] = t;
  trows[t] = make_int2(r1, r2);
}

// ---------------- GEMM1: h = silu(x@Wg^T) * (x@Wu^T), gathered rows ---------
#define BM 128
#define BN 128
#define BK 64

__global__ __launch_bounds__(256) void gemm_gateup(
    const unsigned short* __restrict__ xb,   // [N_TOK, D] bf16
    const unsigned short* __restrict__ wg,   // [E*H, D] bf16
    const unsigned short* __restrict__ wu,   // [E*H, D] bf16
    const int* __restrict__ cnt, const int* __restrict__ off,
    const int* __restrict__ assign,
    unsigned short* __restrict__ hbuf) {     // [N_ASSIGN, H] bf16
  int e = blockIdx.z;
  int nrows = cnt[e];
  int row0 = blockIdx.y * BM;
  if (row0 >= nrows) return;
  int col0 = blockIdx.x * BN;
  int base = off[e];

  __shared__ unsigned short sA[BM][BK];
  __shared__ unsigned short sBg[BN][BK];
  __shared__ unsigned short sBu[BN][BK];

  int tid = threadIdx.x;
  int srow = tid >> 3;            // 0..31: staging row group
  int scol8 = (tid & 7) * 8;      // bf16 col base (16B per lane)

  // token sources for the 4 A-rows this lane stages (clamped for partial tiles)
  const unsigned short* asrc[4];
  const unsigned short* gsrc[4];
  const unsigned short* usrc[4];
#pragma unroll
  for (int i = 0; i < 4; i++) {
    int r = row0 + srow + 32 * i;
    int tok = (r < nrows) ? assign[base + r] : assign[base];
    asrc[i] = xb + (size_t)tok * D_DIM + scol8;
    int wrow = e * H_DIM + col0 + srow + 32 * i;
    gsrc[i] = wg + (size_t)wrow * D_DIM + scol8;
    usrc[i] = wu + (size_t)wrow * D_DIM + scol8;
  }

  int wr = (tid >> 7) & 1, wc = (tid >> 6) & 1;
  int lane = tid & 63;
  int fr = lane & 15;
  int fk = (lane >> 4) * 8;

  f32x4 accg[4][4], accu[4][4];
#pragma unroll
  for (int a = 0; a < 4; a++)
#pragma unroll
    for (int b = 0; b < 4; b++) {
      accg[a][b] = (f32x4){0.f, 0.f, 0.f, 0.f};
      accu[a][b] = (f32x4){0.f, 0.f, 0.f, 0.f};
    }

  for (int k0 = 0; k0 < D_DIM; k0 += BK) {
#pragma unroll
    for (int i = 0; i < 4; i++) {
      gload_lds16(asrc[i] + k0, &sA[srow + 32 * i][scol8]);
      gload_lds16(gsrc[i] + k0, &sBg[srow + 32 * i][scol8]);
      gload_lds16(usrc[i] + k0, &sBu[srow + 32 * i][scol8]);
    }
    __syncthreads();
#pragma unroll
    for (int ks = 0; ks < 2; ks++) {
      short8 af[4], bg[4], bu[4];
#pragma unroll
      for (int mb = 0; mb < 4; mb++)
        af[mb] = *(const short8*)&sA[wr * 64 + mb * 16 + fr][ks * 32 + fk];
#pragma unroll
      for (int nb = 0; nb < 4; nb++) {
        bg[nb] = *(const short8*)&sBg[wc * 64 + nb * 16 + fr][ks * 32 + fk];
        bu[nb] = *(const short8*)&sBu[wc * 64 + nb * 16 + fr][ks * 32 + fk];
      }
#pragma unroll
      for (int mb = 0; mb < 4; mb++)
#pragma unroll
        for (int nb = 0; nb < 4; nb++) {
          accg[mb][nb] = __builtin_amdgcn_mfma_f32_16x16x32_bf16(af[mb], bg[nb], accg[mb][nb], 0, 0, 0);
          accu[mb][nb] = __builtin_amdgcn_mfma_f32_16x16x32_bf16(af[mb], bu[nb], accu[mb][nb], 0, 0, 0);
        }
    }
    __syncthreads();
  }

  int rowlim = nrows - row0;
#pragma unroll
  for (int mb = 0; mb < 4; mb++)
#pragma unroll
    for (int r = 0; r < 4; r++) {
      int lrow = wr * 64 + mb * 16 + (lane >> 4) * 4 + r;
      if (lrow < rowlim) {
        size_t hrow = (size_t)(base + row0 + lrow);
#pragma unroll
        for (int nb = 0; nb < 4; nb++) {
          float g = accg[mb][nb][r], u = accu[mb][nb][r];
          float hval = g / (1.f + __expf(-g)) * u;   // silu(g)*u
          hbuf[hrow * H_DIM + col0 + wc * 64 + nb * 16 + (lane & 15)] = f2bf(hval);
        }
      }
    }
}

// ---------------- GEMM2: e_out = h @ Wd^T (rows already expert-contiguous) --
__global__ __launch_bounds__(256) void gemm_down(
    const unsigned short* __restrict__ hbuf,  // [N_ASSIGN, H] bf16
    const unsigned short* __restrict__ wd,    // [E*D, H] bf16
    const int* __restrict__ cnt, const int* __restrict__ off,
    unsigned short* __restrict__ eo) {        // [N_ASSIGN, D] bf16
  int e = blockIdx.z;
  int nrows = cnt[e];
  int row0 = blockIdx.y * BM;
  if (row0 >= nrows) return;
  int col0 = blockIdx.x * BN;   // d cols (1024/128 = 8 tiles)
  int base = off[e];

  __shared__ unsigned short sA[BM][BK];
  __shared__ unsigned short sB[BN][BK];

  int tid = threadIdx.x;
  int srow = tid >> 3;
  int scol8 = (tid & 7) * 8;

  const unsigned short* asrc[4];
  const unsigned short* bsrc[4];
#pragma unroll
  for (int i = 0; i < 4; i++) {
    int r = row0 + srow + 32 * i;
    int hrow = base + ((r < nrows) ? r : 0);
    asrc[i] = hbuf + (size_t)hrow * H_DIM + scol8;
    int wrow = e * D_DIM + col0 + srow + 32 * i;
    bsrc[i] = wd + (size_t)wrow * H_DIM + scol8;
  }

  int wr = (tid >> 7) & 1, wc = (tid >> 6) & 1;
  int lane = tid & 63;
  int fr = lane & 15;
  int fk = (lane >> 4) * 8;

  f32x4 acc[4][4];
#pragma unroll
  for (int a = 0; a < 4; a++)
#pragma unroll
    for (int b = 0; b < 4; b++) acc[a][b] = (f32x4){0.f, 0.f, 0.f, 0.f};

  for (int k0 = 0; k0 < H_DIM; k0 += BK) {
#pragma unroll
    for (int i = 0; i < 4; i++) {
      gload_lds16(asrc[i] + k0, &sA[srow + 32 * i][scol8]);
      gload_lds16(bsrc[i] + k0, &sB[srow + 32 * i][scol8]);
    }
    __syncthreads();
#pragma unroll
    for (int ks = 0; ks < 2; ks++) {
      short8 af[4], bf[4];
#pragma unroll
      for (int mb = 0; mb < 4; mb++)
        af[mb] = *(const short8*)&sA[wr * 64 + mb * 16 + fr][ks * 32 + fk];
#pragma unroll
      for (int nb = 0; nb < 4; nb++)
        bf[nb] = *(const short8*)&sB[wc * 64 + nb * 16 + fr][ks * 32 + fk];
#pragma unroll
      for (int mb = 0; mb < 4; mb++)
#pragma unroll
        for (int nb = 0; nb < 4; nb++)
          acc[mb][nb] = __builtin_amdgcn_mfma_f32_16x16x32_bf16(af[mb], bf[nb], acc[mb][nb], 0, 0, 0);
    }
    __syncthreads();
  }

  int rowlim = nrows - row0;
#pragma unroll
  for (int mb = 0; mb < 4; mb++)
#pragma unroll
    for (int r = 0; r < 4; r++) {
      int lrow = wr * 64 + mb * 16 + (lane >> 4) * 4 + r;
      if (lrow < rowlim) {
        size_t orow = (size_t)(base + row0 + lrow);
#pragma unroll
        for (int nb = 0; nb < 4; nb++)
          eo[orow * D_DIM + col0 + wc * 64 + nb * 16 + (lane & 15)] = f2bf(acc[mb][nb][r]);
      }
    }
}

// ---------------- combine: out[t] = w1*eo[r1] + w2*eo[r2] -------------------
__global__ __launch_bounds__(256) void combine_kernel(
    const unsigned short* __restrict__ eo, const int2* __restrict__ trows,
    const float2* __restrict__ tiw, float* __restrict__ out) {
  int t = blockIdx.x;
  int2 r = trows[t];
  float2 w = tiw[t];
  int c = threadIdx.x * 4;
  ushort4 a = *(const ushort4*)&eo[(size_t)r.x * D_DIM + c];
  ushort4 b = *(const ushort4*)&eo[(size_t)r.y * D_DIM + c];
  float4 o;
  o.x = w.x * bf2f(a.x) + w.y * bf2f(b.x);
  o.y = w.x * bf2f(a.y) + w.y * bf2f(b.y);
  o.z = w.x * bf2f(a.z) + w.y * bf2f(b.z);
  o.w = w.x * bf2f(a.w) + w.y * bf2f(b.w);
  *(float4*)&out[(size_t)t * D_DIM + c] = o;
}

extern "C" void kernel_launch(void* const* d_in, const int* in_sizes, int n_in,
                              void* d_out, int out_size, void* d_ws, size_t ws_size,
                              hipStream_t stream) {
  const float* x  = (const float*)d_in[0];
  const float* rw = (const float*)d_in[1];
  const float* rb = (const float*)d_in[2];
  const float* wg = (const float*)d_in[3];
  const float* wu = (const float*)d_in[4];
  const float* wd = (const float*)d_in[5];
  float* out = (float*)d_out;

  char* ws = (char*)d_ws;
  size_t o = 0;
  auto alloc = [&](size_t b) { char* p = ws + o; o += (b + 255) & ~(size_t)255; return p; };
  unsigned short* xb  = (unsigned short*)alloc((size_t)N_TOK * D_DIM * 2);       // 16.8 MB
  unsigned short* wgb = (unsigned short*)alloc((size_t)N_EXP * H_DIM * D_DIM * 2); // 33.6 MB
  unsigned short* wub = (unsigned short*)alloc((size_t)N_EXP * H_DIM * D_DIM * 2); // 33.6 MB
  unsigned short* wdb = (unsigned short*)alloc((size_t)N_EXP * D_DIM * H_DIM * 2); // 33.6 MB
  unsigned short* hb  = (unsigned short*)alloc((size_t)N_ASSIGN * H_DIM * 2);     // 67.1 MB
  unsigned short* eob = (unsigned short*)alloc((size_t)N_ASSIGN * D_DIM * 2);     // 33.6 MB
  int*    assign = (int*)alloc(N_ASSIGN * 4);
  int4*   tiidx  = (int4*)alloc(N_TOK * 16);
  float2* tiw    = (float2*)alloc(N_TOK * 8);
  int2*   trows  = (int2*)alloc(N_TOK * 8);
  int*    cnt    = (int*)alloc(64);
  int*    off    = (int*)alloc(64);

  const int wElems = N_EXP * H_DIM * D_DIM;  // 16,777,216

  zero_cnt_kernel<<<1, 64, 0, stream>>>(cnt);
  cvt_bf16_kernel<<<wElems / 1024, 256, 0, stream>>>(wg, wgb, wElems);
  cvt_bf16_kernel<<<wElems / 1024, 256, 0, stream>>>(wu, wub, wElems);
  cvt_bf16_kernel<<<wElems / 1024, 256, 0, stream>>>(wd, wdb, wElems);
  router_kernel<<<N_TOK / 4, 256, 0, stream>>>(x, rw, rb, xb, tiidx, tiw, cnt);
  offsets_kernel<<<1, 1, 0, stream>>>(cnt, off);
  scatter_kernel<<<N_TOK / 256, 256, 0, stream>>>(tiidx, off, assign, trows);
  gemm_gateup<<<dim3(H_DIM / BN, N_TOK / BM, N_EXP), 256, 0, stream>>>(
      xb, wgb, wub, cnt, off, assign, hb);
  gemm_down<<<dim3(D_DIM / BN, N_TOK / BM, N_EXP), 256, 0, stream>>>(
      hb, wdb, cnt, off, eob);
  combine_kernel<<<N_TOK, 256, 0, stream>>>(eob, trows, tiw, out);
}

// Round 2
// 553.058 us; speedup vs baseline: 1.3806x; 1.3806x over previous
//
#include <hip/hip_runtime.h>
#include <hip/hip_bf16.h>
#include <stdint.h>

// SparseMoE top-2/8, N=8192, D=1024, H=2048, fp32 in/out.
// R2: (1) T2 XOR-swizzle both-sides (pre-swizzled global src + swizzled ds_read)
//     to kill the 16-way LDS bank conflict that capped R1 at ~342 TF;
//     (2) gate/up weights interleaved at 16-row granularity -> single GEMM,
//     lane-local silu*mul epilogue, 2 LDS buffers instead of 3;
//     (3) minimum-2-phase double-buffered schedule (stage-next, compute-cur,
//     one barrier per K-step).

#define N_TOK 8192
#define D_DIM 1024
#define H_DIM 2048
#define N_EXP 8
#define N_ASSIGN (N_TOK * 2)
#define BM 128
#define BN 128
#define BK 64

typedef __attribute__((ext_vector_type(8))) short short8;   // bf16x8 MFMA frag
typedef __attribute__((ext_vector_type(4))) float f32x4;    // MFMA acc frag

__device__ __forceinline__ unsigned short f2bf(float f) {
  union { float f; unsigned int u; } v; v.f = f;
  unsigned int r = v.u + 0x7fffu + ((v.u >> 16) & 1u);  // RTNE
  return (unsigned short)(r >> 16);
}
__device__ __forceinline__ float bf2f(unsigned short u) {
  union { float f; unsigned int u; } v; v.u = ((unsigned int)u) << 16; return v.f;
}
__device__ __forceinline__ void gload_lds16(const void* g, void* l) {
  __builtin_amdgcn_global_load_lds((const __attribute__((address_space(1))) void*)g,
                                   (__attribute__((address_space(3))) void*)l, 16, 0, 0);
}

// ---------------- tiny setup kernels ----------------
__global__ void zero_cnt_kernel(int* cnt) {
  if (threadIdx.x < N_EXP) cnt[threadIdx.x] = 0;
}

// plain fp32 -> bf16 convert (down weights)
__global__ void cvt_down_kernel(const float* __restrict__ src,
                                unsigned short* __restrict__ dst, int n) {
  int i = (blockIdx.x * 256 + threadIdx.x) * 4;
  if (i >= n) return;
  float4 v = *(const float4*)(src + i);
  ushort4 o;
  o.x = f2bf(v.x); o.y = f2bf(v.y); o.z = f2bf(v.z); o.w = f2bf(v.w);
  *(ushort4*)(dst + i) = o;
}

// gate/up -> interleaved wgu [E][4096][D]: 16-row group 2g   = gate rows [16g,16g+16)
//                                          16-row group 2g+1 = up   rows [16g,16g+16)
__global__ void cvt_gu_kernel(const float* __restrict__ g, const float* __restrict__ u,
                              unsigned short* __restrict__ dst) {
  int up = blockIdx.y;
  const float* src = up ? u : g;
  size_t i = ((size_t)blockIdx.x * 256 + threadIdx.x) * 4;
  float4 v = *(const float4*)(src + i);
  int j = (int)(i >> 10);              // source row = e*H + jj
  int e = j >> 11;
  int jj = j & (H_DIM - 1);
  int n = ((jj >> 4) << 5) + (up ? 16 : 0) + (jj & 15);
  size_t di = (((size_t)(e << 12) + n) << 10) + (i & 1023);
  ushort4 o;
  o.x = f2bf(v.x); o.y = f2bf(v.y); o.z = f2bf(v.z); o.w = f2bf(v.w);
  *(ushort4*)(dst + di) = o;
}

// ---------------- router: fp32 logits, softmax, top-2, slot assignment ------
__global__ __launch_bounds__(256) void router_kernel(
    const float* __restrict__ x, const float* __restrict__ rw,
    const float* __restrict__ rb,
    unsigned short* __restrict__ xb,          // bf16 copy of x
    int4* __restrict__ tiidx,                 // (e1,e2,slot1,slot2)
    float2* __restrict__ tiw,                 // (w1,w2) normalized
    int* __restrict__ cnt) {
  __shared__ float sw[N_EXP][D_DIM];          // 32 KB router weights
  int tid = threadIdx.x;
  for (int i = tid * 4; i < N_EXP * D_DIM; i += 256 * 4)
    *(float4*)&sw[0][i] = *(const float4*)(rw + i);
  __syncthreads();

  int wave = tid >> 6, lane = tid & 63;
  int t = blockIdx.x * 4 + wave;
  const float* xr = x + (size_t)t * D_DIM;
  float xs[16];
#pragma unroll
  for (int j = 0; j < 16; j++) xs[j] = xr[lane + 64 * j];
#pragma unroll
  for (int j = 0; j < 16; j++) xb[(size_t)t * D_DIM + lane + 64 * j] = f2bf(xs[j]);

  float logit[N_EXP];
#pragma unroll
  for (int e = 0; e < N_EXP; e++) {
    float acc = 0.f;
#pragma unroll
    for (int j = 0; j < 16; j++) acc += xs[j] * sw[e][lane + 64 * j];
#pragma unroll
    for (int off = 32; off; off >>= 1) acc += __shfl_xor(acc, off);
    logit[e] = acc + rb[e];
  }
  if (lane == 0) {
    float m = logit[0];
#pragma unroll
    for (int e = 1; e < N_EXP; e++) m = fmaxf(m, logit[e]);
    float p[N_EXP], S = 0.f;
#pragma unroll
    for (int e = 0; e < N_EXP; e++) { p[e] = expf(logit[e] - m); S += p[e]; }
#pragma unroll
    for (int e = 0; e < N_EXP; e++) p[e] /= S;
    int i1 = 0; float v1 = p[0];
#pragma unroll
    for (int e = 1; e < N_EXP; e++) if (p[e] > v1) { v1 = p[e]; i1 = e; }
    int i2 = -1; float v2 = -1.f;
#pragma unroll
    for (int e = 0; e < N_EXP; e++) if (e != i1 && p[e] > v2) { v2 = p[e]; i2 = e; }
    float inv = 1.f / (v1 + v2 + 1e-9f);
    int s1 = atomicAdd(&cnt[i1], 1);
    int s2 = atomicAdd(&cnt[i2], 1);
    tiidx[t] = make_int4(i1, i2, s1, s2);
    tiw[t] = make_float2(v1 * inv, v2 * inv);
  }
}

__global__ void offsets_kernel(const int* __restrict__ cnt, int* __restrict__ off) {
  if (threadIdx.x == 0) {
    int a = 0;
    for (int e = 0; e < N_EXP; e++) { off[e] = a; a += cnt[e]; }
    off[N_EXP] = a;
  }
}

__global__ void scatter_kernel(const int4* __restrict__ tiidx,
                               const int* __restrict__ off,
                               int* __restrict__ assign, int2* __restrict__ trows) {
  int t = blockIdx.x * 256 + threadIdx.x;
  if (t >= N_TOK) return;
  int4 ti = tiidx[t];
  int r1 = off[ti.x] + ti.z;
  int r2 = off[ti.y] + ti.w;
  assign[r1] = t;
  assign[r2] = t;
  trows[t] = make_int2(r1, r2);
}

// ---------------- GEMM1: fused gate+up over interleaved wgu ----------------
// output N-range [0, 4096): even 16-col groups are gate, odd are up for the
// same h columns -> acc[mb][2p] (gate) pairs with acc[mb][2p+1] (up).
__global__ __launch_bounds__(256) void gemm_gateup(
    const unsigned short* __restrict__ xb,    // [N_TOK, D] bf16
    const unsigned short* __restrict__ wgu,   // [E*4096, D] bf16 interleaved
    const int* __restrict__ cnt, const int* __restrict__ off,
    const int* __restrict__ assign,
    unsigned short* __restrict__ hbuf) {      // [N_ASSIGN, H] bf16
  int e = blockIdx.z;
  int nrows = cnt[e];
  int row0 = blockIdx.y * BM;
  if (row0 >= nrows) return;
  int col0 = blockIdx.x * BN;                 // in [0, 4096)
  int base = off[e];

  __shared__ unsigned short sA[2][BM][BK];
  __shared__ unsigned short sB[2][BN][BK];

  int tid = threadIdx.x;
  int srow = tid >> 3;                        // 0..31
  int dst8 = (tid & 7) * 8;                   // linear LDS chunk (required by gload_lds)
  int src8 = ((tid & 7) ^ (srow & 7)) * 8;    // pre-swizzled global column

  const unsigned short* asrc[4];
  const unsigned short* bsrc[4];
#pragma unroll
  for (int i = 0; i < 4; i++) {
    int r = row0 + srow + 32 * i;
    int tok = (r < nrows) ? assign[base + r] : assign[base];
    asrc[i] = xb + (size_t)tok * D_DIM + src8;
    int wrow = (e << 12) + col0 + srow + 32 * i;
    bsrc[i] = wgu + (size_t)wrow * D_DIM + src8;
  }

  int wr = (tid >> 7) & 1, wc = (tid >> 6) & 1;
  int lane = tid & 63;
  int fr = lane & 15;
  int fk = (lane >> 4) * 8;
  int rx = (fr & 7) * 8;                      // read-side swizzle XOR

  f32x4 acc[4][4];
#pragma unroll
  for (int a = 0; a < 4; a++)
#pragma unroll
    for (int b = 0; b < 4; b++) acc[a][b] = (f32x4){0.f, 0.f, 0.f, 0.f};

#define STAGE(bf, k0)                                                       \
  _Pragma("unroll")                                                         \
  for (int i = 0; i < 4; i++) {                                             \
    gload_lds16(asrc[i] + (k0), &sA[bf][srow + 32 * i][dst8]);              \
    gload_lds16(bsrc[i] + (k0), &sB[bf][srow + 32 * i][dst8]);              \
  }
#define COMPUTE(bf)                                                         \
  _Pragma("unroll")                                                         \
  for (int ks = 0; ks < 2; ks++) {                                          \
    short8 af[4], bq[4];                                                    \
    int c = (ks * 32 + fk) ^ rx;                                            \
    _Pragma("unroll")                                                       \
    for (int mb = 0; mb < 4; mb++)                                          \
      af[mb] = *(const short8*)&sA[bf][wr * 64 + mb * 16 + fr][c];          \
    _Pragma("unroll")                                                       \
    for (int nb = 0; nb < 4; nb++)                                          \
      bq[nb] = *(const short8*)&sB[bf][wc * 64 + nb * 16 + fr][c];          \
    _Pragma("unroll")                                                       \
    for (int mb = 0; mb < 4; mb++)                                          \
      _Pragma("unroll")                                                     \
      for (int nb = 0; nb < 4; nb++)                                        \
        acc[mb][nb] = __builtin_amdgcn_mfma_f32_16x16x32_bf16(              \
            af[mb], bq[nb], acc[mb][nb], 0, 0, 0);                          \
  }

  STAGE(0, 0);
  __syncthreads();
  for (int k0 = 0; k0 < D_DIM - 128; k0 += 128) {
    STAGE(1, k0 + 64);  COMPUTE(0); __syncthreads();
    STAGE(0, k0 + 128); COMPUTE(1); __syncthreads();
  }
  STAGE(1, D_DIM - 64); COMPUTE(0); __syncthreads();
  COMPUTE(1);
#undef STAGE
#undef COMPUTE

  int rowlim = nrows - row0;
#pragma unroll
  for (int mb = 0; mb < 4; mb++)
#pragma unroll
    for (int r = 0; r < 4; r++) {
      int lrow = wr * 64 + mb * 16 + (lane >> 4) * 4 + r;
      if (lrow < rowlim) {
        size_t hrow = (size_t)(base + row0 + lrow);
#pragma unroll
        for (int nbp = 0; nbp < 2; nbp++) {
          float g = acc[mb][2 * nbp][r], u = acc[mb][2 * nbp + 1][r];
          float hv = g / (1.f + __expf(-g)) * u;     // silu(g)*u
          int hcol = (col0 >> 1) + wc * 32 + nbp * 16 + (lane & 15);
          hbuf[hrow * H_DIM + hcol] = f2bf(hv);
        }
      }
    }
}

// ---------------- GEMM2: e_out = h @ Wd^T -----------------------------------
__global__ __launch_bounds__(256) void gemm_down(
    const unsigned short* __restrict__ hbuf,  // [N_ASSIGN, H] bf16
    const unsigned short* __restrict__ wd,    // [E*D, H] bf16
    const int* __restrict__ cnt, const int* __restrict__ off,
    unsigned short* __restrict__ eo) {        // [N_ASSIGN, D] bf16
  int e = blockIdx.z;
  int nrows = cnt[e];
  int row0 = blockIdx.y * BM;
  if (row0 >= nrows) return;
  int col0 = blockIdx.x * BN;                 // d cols
  int base = off[e];

  __shared__ unsigned short sA[2][BM][BK];
  __shared__ unsigned short sB[2][BN][BK];

  int tid = threadIdx.x;
  int srow = tid >> 3;
  int dst8 = (tid & 7) * 8;
  int src8 = ((tid & 7) ^ (srow & 7)) * 8;

  const unsigned short* asrc[4];
  const unsigned short* bsrc[4];
#pragma unroll
  for (int i = 0; i < 4; i++) {
    int r = row0 + srow + 32 * i;
    int hrow = base + ((r < nrows) ? r : 0);
    asrc[i] = hbuf + (size_t)hrow * H_DIM + src8;
    int wrow = e * D_DIM + col0 + srow + 32 * i;
    bsrc[i] = wd + (size_t)wrow * H_DIM + src8;
  }

  int wr = (tid >> 7) & 1, wc = (tid >> 6) & 1;
  int lane = tid & 63;
  int fr = lane & 15;
  int fk = (lane >> 4) * 8;
  int rx = (fr & 7) * 8;

  f32x4 acc[4][4];
#pragma unroll
  for (int a = 0; a < 4; a++)
#pragma unroll
    for (int b = 0; b < 4; b++) acc[a][b] = (f32x4){0.f, 0.f, 0.f, 0.f};

#define STAGE(bf, k0)                                                       \
  _Pragma("unroll")                                                         \
  for (int i = 0; i < 4; i++) {                                             \
    gload_lds16(asrc[i] + (k0), &sA[bf][srow + 32 * i][dst8]);              \
    gload_lds16(bsrc[i] + (k0), &sB[bf][srow + 32 * i][dst8]);              \
  }
#define COMPUTE(bf)                                                         \
  _Pragma("unroll")                                                         \
  for (int ks = 0; ks < 2; ks++) {                                          \
    short8 af[4], bq[4];                                                    \
    int c = (ks * 32 + fk) ^ rx;                                            \
    _Pragma("unroll")                                                       \
    for (int mb = 0; mb < 4; mb++)                                          \
      af[mb] = *(const short8*)&sA[bf][wr * 64 + mb * 16 + fr][c];          \
    _Pragma("unroll")                                                       \
    for (int nb = 0; nb < 4; nb++)                                          \
      bq[nb] = *(const short8*)&sB[bf][wc * 64 + nb * 16 + fr][c];          \
    _Pragma("unroll")                                                       \
    for (int mb = 0; mb < 4; mb++)                                          \
      _Pragma("unroll")                                                     \
      for (int nb = 0; nb < 4; nb++)                                        \
        acc[mb][nb] = __builtin_amdgcn_mfma_f32_16x16x32_bf16(              \
            af[mb], bq[nb], acc[mb][nb], 0, 0, 0);                          \
  }

  STAGE(0, 0);
  __syncthreads();
  for (int k0 = 0; k0 < H_DIM - 128; k0 += 128) {
    STAGE(1, k0 + 64);  COMPUTE(0); __syncthreads();
    STAGE(0, k0 + 128); COMPUTE(1); __syncthreads();
  }
  STAGE(1, H_DIM - 64); COMPUTE(0); __syncthreads();
  COMPUTE(1);
#undef STAGE
#undef COMPUTE

  int rowlim = nrows - row0;
#pragma unroll
  for (int mb = 0; mb < 4; mb++)
#pragma unroll
    for (int r = 0; r < 4; r++) {
      int lrow = wr * 64 + mb * 16 + (lane >> 4) * 4 + r;
      if (lrow < rowlim) {
        size_t orow = (size_t)(base + row0 + lrow);
#pragma unroll
        for (int nb = 0; nb < 4; nb++)
          eo[orow * D_DIM + col0 + wc * 64 + nb * 16 + (lane & 15)] = f2bf(acc[mb][nb][r]);
      }
    }
}

// ---------------- combine: out[t] = w1*eo[r1] + w2*eo[r2] -------------------
__global__ __launch_bounds__(256) void combine_kernel(
    const unsigned short* __restrict__ eo, const int2* __restrict__ trows,
    const float2* __restrict__ tiw, float* __restrict__ out) {
  int t = blockIdx.x;
  int2 r = trows[t];
  float2 w = tiw[t];
  int c = threadIdx.x * 4;
  ushort4 a = *(const ushort4*)&eo[(size_t)r.x * D_DIM + c];
  ushort4 b = *(const ushort4*)&eo[(size_t)r.y * D_DIM + c];
  float4 o;
  o.x = w.x * bf2f(a.x) + w.y * bf2f(b.x);
  o.y = w.x * bf2f(a.y) + w.y * bf2f(b.y);
  o.z = w.x * bf2f(a.z) + w.y * bf2f(b.z);
  o.w = w.x * bf2f(a.w) + w.y * bf2f(b.w);
  *(float4*)&out[(size_t)t * D_DIM + c] = o;
}

extern "C" void kernel_launch(void* const* d_in, const int* in_sizes, int n_in,
                              void* d_out, int out_size, void* d_ws, size_t ws_size,
                              hipStream_t stream) {
  const float* x  = (const float*)d_in[0];
  const float* rw = (const float*)d_in[1];
  const float* rb = (const float*)d_in[2];
  const float* wg = (const float*)d_in[3];
  const float* wu = (const float*)d_in[4];
  const float* wd = (const float*)d_in[5];
  float* out = (float*)d_out;

  char* ws = (char*)d_ws;
  size_t o = 0;
  auto alloc = [&](size_t b) { char* p = ws + o; o += (b + 255) & ~(size_t)255; return p; };
  unsigned short* xb  = (unsigned short*)alloc((size_t)N_TOK * D_DIM * 2);           // 16.8 MB
  unsigned short* wgu = (unsigned short*)alloc((size_t)N_EXP * 4096 * D_DIM * 2);    // 67.1 MB
  unsigned short* wdb = (unsigned short*)alloc((size_t)N_EXP * D_DIM * H_DIM * 2);   // 33.6 MB
  unsigned short* hb  = (unsigned short*)alloc((size_t)N_ASSIGN * H_DIM * 2);        // 67.1 MB
  unsigned short* eob = (unsigned short*)alloc((size_t)N_ASSIGN * D_DIM * 2);        // 33.6 MB
  int*    assign = (int*)alloc(N_ASSIGN * 4);
  int4*   tiidx  = (int4*)alloc(N_TOK * 16);
  float2* tiw    = (float2*)alloc(N_TOK * 8);
  int2*   trows  = (int2*)alloc(N_TOK * 8);
  int*    cnt    = (int*)alloc(64);
  int*    off    = (int*)alloc(64);

  const int wElems = N_EXP * H_DIM * D_DIM;  // 16,777,216

  zero_cnt_kernel<<<1, 64, 0, stream>>>(cnt);
  cvt_gu_kernel<<<dim3(wElems / 1024, 2), 256, 0, stream>>>(wg, wu, wgu);
  cvt_down_kernel<<<wElems / 1024, 256, 0, stream>>>(wd, wdb, wElems);
  router_kernel<<<N_TOK / 4, 256, 0, stream>>>(x, rw, rb, xb, tiidx, tiw, cnt);
  offsets_kernel<<<1, 1, 0, stream>>>(cnt, off);
  scatter_kernel<<<N_TOK / 256, 256, 0, stream>>>(tiidx, off, assign, trows);
  gemm_gateup<<<dim3(4096 / BN, N_TOK / BM, N_EXP), 256, 0, stream>>>(
      xb, wgu, cnt, off, assign, hb);
  gemm_down<<<dim3(D_DIM / BN, N_TOK / BM, N_EXP), 256, 0, stream>>>(
      hb, wdb, cnt, off, eob);
  combine_kernel<<<N_TOK, 256, 0, stream>>>(eob, trows, tiw, out);
}